// Round 4
// baseline (296.886 us; speedup 1.0000x reference)
//
#include <hip/hip_runtime.h>
#include <hip/hip_bf16.h>
#include <stdint.h>

// TemporalAttention: x[B,T,C] -> qkv proj -> causal MHA -> out proj.
// B=4 T=2048 C=1024 H=16 D=64. Inputs fp32, output fp32; internal bf16 MFMA.
//
// R9 post-mortem: shared-frag fusion cut LDS traffic (conflicts -19%) but
// dur 84->98us: the shared sPw region serialized both jobs' P roundtrips
// behind 4 lgkmcnt(0) drains/iter, and bounds(256,3) lost residency.
// R10: keep fusion (LDS floor ~55us), de-serialize: per-(wave,job) private
// P regions (sP 128 rows, LDS 36864B, still 4 blocks/CU); WAR fences
// deleted (staging barriers already drain lgkm each iter); ONE RAW drain
// per iter; bounds(256,4) restored.

using bf16 = __hip_bfloat16;
typedef __attribute__((ext_vector_type(8))) __bf16 bf16x8;
typedef __attribute__((ext_vector_type(8))) unsigned short u16x8;
typedef __attribute__((ext_vector_type(4))) unsigned short u16x4;
typedef __attribute__((ext_vector_type(4))) float f32x4;
typedef unsigned short ushort_t;

#define MFMA16(a, b, c) __builtin_amdgcn_mfma_f32_16x16x32_bf16((a), (b), (c), 0, 0, 0)

__device__ __forceinline__ bf16x8 ld_frag(const ushort_t* p) {
  const u16x8 u = *(const u16x8*)p;
  return __builtin_bit_cast(bf16x8, u);
}

__device__ __forceinline__ ushort_t f2bf(float f) {
  return __builtin_bit_cast(ushort_t, __float2bfloat16(f));
}

// async global->LDS, 16B/lane; lds base wave-uniform, lane l -> base+l*16.
__device__ __forceinline__ void gl2lds16(const void* g, void* lds) {
  __builtin_amdgcn_global_load_lds((const __attribute__((address_space(1))) void*)g,
                                   (__attribute__((address_space(3))) void*)lds,
                                   16, 0, 0);
}

// ---------------------------------------------------------------------------
// Dtype detector (hedge; fp32 established). flag=1 -> fp32.
// ---------------------------------------------------------------------------
__global__ void detect_dtype(const ushort_t* __restrict__ x, int* __restrict__ flag) {
  __shared__ int red[256];
  const int tid = threadIdx.x;
  int cnt = 0;
  for (int i = tid; i < 4096; i += 256) {
    const int e = (x[i] & 0x7FFF) >> 7;
    cnt += (e >= 117 && e <= 133) ? 1 : 0;
  }
  red[tid] = cnt;
  __syncthreads();
  for (int s = 128; s > 0; s >>= 1) {
    if (tid < s) red[tid] += red[tid + s];
    __syncthreads();
  }
  if (tid == 0) *flag = (red[0] < 3072) ? 1 : 0;
}

// ---------------------------------------------------------------------------
// fp32 -> bf16 (or copy if flag==0). n multiple of 2048.
// ---------------------------------------------------------------------------
__global__ void cvt_to_bf16(const void* __restrict__ in, ushort_t* __restrict__ out,
                            int n, const int* __restrict__ flag) {
  const int i = (blockIdx.x * 256 + threadIdx.x) * 8;
  if (i >= n) return;
  if (*flag) {
    const float* p = (const float*)in + i;
    const float4 f0 = *(const float4*)p;
    const float4 f1 = *(const float4*)(p + 4);
    u16x8 u;
    u[0] = f2bf(f0.x); u[1] = f2bf(f0.y); u[2] = f2bf(f0.z); u[3] = f2bf(f0.w);
    u[4] = f2bf(f1.x); u[5] = f2bf(f1.y); u[6] = f2bf(f1.z); u[7] = f2bf(f1.w);
    *(u16x8*)(out + i) = u;
  } else {
    *(u16x8*)(out + i) = *(const u16x8*)((const ushort_t*)in + i);
  }
}

// ---------------------------------------------------------------------------
// NT GEMM: C[M,N] = A[M,K]*B[N,K]^T. 128x128 tile, 4 waves 2x2, BK=32,
// 16x16x32 bf16 MFMA. A: bf16, gl2lds staging (m97-verbatim, plain layout).
// B: bf16 via gl2lds when bF==0; fp32 register-staged+cvt when bF==1
// (ws-starved fallback). EPI==0: fp32 store. EPI==1: scatter q/k [B,H,T,D],
// V transposed [B,H,D,T].
// ---------------------------------------------------------------------------
template <int EPI>
__global__ __launch_bounds__(256, 2)
void gemm_nt(const ushort_t* __restrict__ A, const void* __restrict__ Bw,
             const int* __restrict__ flag, int bExt,
             float* __restrict__ C0, ushort_t* __restrict__ Qo,
             ushort_t* __restrict__ Ko, ushort_t* __restrict__ Vt,
             int M, int N, int Kd) {
  __shared__ ushort_t sA[128 * 32];
  __shared__ ushort_t sB[128 * 32];
  const int tid = threadIdx.x;
  const int wave = tid >> 6, lane = tid & 63;
  const int quad = lane >> 4, l16 = lane & 15;
  const int wm = wave >> 1, wn = wave & 1;
  const long m0 = (long)blockIdx.y * 128;
  const long n0 = (long)blockIdx.x * 128;
  const int bF = bExt ? *flag : 0;

  f32x4 acc[4][4];
#pragma unroll
  for (int i = 0; i < 4; ++i)
#pragma unroll
    for (int j = 0; j < 4; ++j) acc[i][j] = (f32x4){0.f, 0.f, 0.f, 0.f};

  for (int k0 = 0; k0 < Kd; k0 += 32) {
#pragma unroll
    for (int j = 0; j < 2; ++j) {
      const int chunk = wave * 2 + j;     // wave-uniform LDS base
      const int idx = chunk * 64 + lane;  // 0..511: 16B chunk per lane
      const int r = idx >> 2, c = idx & 3;
      gl2lds16(A + (m0 + r) * (long)Kd + k0 + c * 8, (char*)sA + chunk * 1024);
    }
    if (!bF) {
#pragma unroll
      for (int j = 0; j < 2; ++j) {
        const int chunk = wave * 2 + j;
        const int idx = chunk * 64 + lane;
        const int r = idx >> 2, c = idx & 3;
        gl2lds16((const ushort_t*)Bw + (n0 + r) * (long)Kd + k0 + c * 8,
                 (char*)sB + chunk * 1024);
      }
    } else {
#pragma unroll
      for (int t2 = 0; t2 < 2; ++t2) {
        const int idx = t2 * 256 + tid;
        const int r = idx >> 2, c = idx & 3;
        const float* p = (const float*)Bw + (n0 + r) * (long)Kd + k0 + c * 8;
        const float4 f0 = *(const float4*)p;
        const float4 f1 = *(const float4*)(p + 4);
        u16x8 u;
        u[0] = f2bf(f0.x); u[1] = f2bf(f0.y); u[2] = f2bf(f0.z); u[3] = f2bf(f0.w);
        u[4] = f2bf(f1.x); u[5] = f2bf(f1.y); u[6] = f2bf(f1.z); u[7] = f2bf(f1.w);
        *(u16x8*)&sB[r * 32 + c * 8] = u;
      }
    }
    __syncthreads();
    bf16x8 af[4], bfr[4];
#pragma unroll
    for (int i = 0; i < 4; ++i) {
      const int r = wm * 64 + i * 16 + l16;
      af[i] = ld_frag(&sA[r * 32 + quad * 8]);
    }
#pragma unroll
    for (int i = 0; i < 4; ++i) {
      const int r = wn * 64 + i * 16 + l16;
      bfr[i] = ld_frag(&sB[r * 32 + quad * 8]);
    }
#pragma unroll
    for (int i = 0; i < 4; ++i)
#pragma unroll
      for (int j = 0; j < 4; ++j) acc[i][j] = MFMA16(af[i], bfr[j], acc[i][j]);
    __syncthreads();
  }

  // epilogue: C/D layout col=lane&15, row=quad*4+reg (m89-verified)
#pragma unroll
  for (int i = 0; i < 4; ++i) {
#pragma unroll
    for (int j = 0; j < 4; ++j) {
      if (EPI == 0) {
#pragma unroll
        for (int reg = 0; reg < 4; ++reg) {
          const long m = m0 + wm * 64 + i * 16 + quad * 4 + reg;
          const long n = n0 + wn * 64 + j * 16 + l16;
          C0[m * N + n] = acc[i][j][reg];
        }
      } else {
        const long n = n0 + wn * 64 + j * 16 + l16;
        const int which = (int)(n >> 10);  // block-uniform
        const int h = (int)((n >> 6) & 15);
        const int d = (int)(n & 63);
        const long mbase = m0 + wm * 64 + i * 16 + quad * 4;
        const long b = mbase >> 11;
        const long tb = mbase & 2047;
        if (which == 2) {
          u16x4 pk;
#pragma unroll
          for (int reg = 0; reg < 4; ++reg) pk[reg] = f2bf(acc[i][j][reg]);
          *(u16x4*)&Vt[((b * 16 + h) * 64 + d) * 2048 + tb] = pk;
        } else {
          ushort_t* dst = (which == 0) ? Qo : Ko;
#pragma unroll
          for (int reg = 0; reg < 4; ++reg)
            dst[((b * 16 + h) * 2048 + tb + reg) * 64 + d] = f2bf(acc[i][j][reg]);
        }
      }
    }
  }
}

// ---------------------------------------------------------------------------
// Flash attention (causal), S^T/O^T formulation.
// R10: shared kf/vf fusion (R9) + per-(wave,job) private P regions in sP
// (128 rows). WAR fences deleted — the two staging barriers each iteration
// drain lgkm, so prior-iteration P reads are complete before this
// iteration's P writes. One RAW lgkmcnt(0) drain per iteration.
// ---------------------------------------------------------------------------
#define RS 72  // LDS row stride in ushorts (64 + 16B pad)

// softmax over S^T tile held in s[4] (keys = kb+nt*16+reg, q col = l16).
// Mutates s to P values; updates m_i, l_i; rescales oacc on max growth.
__device__ __forceinline__ void softmax_tile(f32x4* s, int kb, int qg, bool need_mask,
                                             float& m_i, float& l_i, f32x4* oacc) {
  float rmax = -1e30f;
  if (need_mask) {  // diagonal tiles only (wave-uniform)
#pragma unroll
    for (int nt = 0; nt < 4; ++nt) {
#pragma unroll
      for (int reg = 0; reg < 4; ++reg) {
        float v = s[nt][reg];
        if (kb + nt * 16 + reg > qg) v = -1e30f;
        s[nt][reg] = v;
        rmax = fmaxf(rmax, v);
      }
    }
  } else {
#pragma unroll
    for (int nt = 0; nt < 4; ++nt) {
#pragma unroll
      for (int reg = 0; reg < 4; ++reg) rmax = fmaxf(rmax, s[nt][reg]);
    }
  }
  rmax = fmaxf(rmax, __shfl_xor(rmax, 16, 64));
  rmax = fmaxf(rmax, __shfl_xor(rmax, 32, 64));
  float mnew = fmaxf(m_i, rmax);
  if (__all(rmax - m_i <= 5.5f)) {
    mnew = m_i;  // defer-max: P bounded by e^5.5 ~ 245, f32 accum tolerates
  } else {
    const float alpha = __expf(m_i - mnew);
    l_i *= alpha;
#pragma unroll
    for (int dt = 0; dt < 4; ++dt) oacc[dt] *= alpha;
    m_i = mnew;
  }
  float rs = 0.f;
#pragma unroll
  for (int nt = 0; nt < 4; ++nt) {
#pragma unroll
    for (int reg = 0; reg < 4; ++reg) {
      const float p = __expf(s[nt][reg] - mnew);
      s[nt][reg] = p;
      rs += p;
    }
  }
  rs += __shfl_xor(rs, 16, 64);
  rs += __shfl_xor(rs, 32, 64);
  l_i += rs;
}

__global__ __launch_bounds__(256, 4)
void attn_causal(const ushort_t* __restrict__ Qg, const ushort_t* __restrict__ Kg,
                 const ushort_t* __restrict__ Vt, ushort_t* __restrict__ Yg) {
  __shared__ ushort_t sK[64 * RS];
  __shared__ ushort_t sV[64 * RS];
  __shared__ ushort_t sP[128 * RS];  // per-(wave,job) 16-row regions; rows 0..63 double as Q staging
  const int tid = threadIdx.x;
  const int wave = tid >> 6, lane = tid & 63;
  const int quad = lane >> 4, l16 = lane & 15;
  const f32x4 ZERO4 = {0.f, 0.f, 0.f, 0.f};
  // XCD-aware bijective remap (hw id = x + 16*y; 16y%8==0 so default XCD=qx%8
  // streams all 64 heads' KV through every XCD L2). Remap so XCD k owns
  // bh in [8k, 8k+8): 8 x 512KB KV = 4MB = one XCD L2.
  const int lin = blockIdx.y * 16 + blockIdx.x;
  const int logical = (lin & 7) * 128 + (lin >> 3);
  const int qx = logical & 15, bh = logical >> 4;
  const int qtA = qx, qtB = 31 - qx;
  const size_t base = (size_t)bh * 2048 * 64;
  ushort_t* sPwB = sP + (wave * 2 + 0) * 16 * RS;
  ushort_t* sPwA = sP + (wave * 2 + 1) * 16 * RS;

  // Q fragments, pre-scaled by 1/sqrt(D)=0.125 (exponent shift: exact in bf16)
  bf16x8 qfA[2], qfB[2];
#pragma unroll
  for (int tile = 0; tile < 2; ++tile) {
    const int qt = tile ? qtB : qtA;
#pragma unroll
    for (int t2 = 0; t2 < 2; ++t2) {
      const int idx = t2 * 256 + tid;
      const int r = idx >> 3, c = idx & 7;
      *(u16x8*)&sP[r * RS + c * 8] =
          *(const u16x8*)(Qg + base + (size_t)(qt * 64 + r) * 64 + c * 8);
    }
    __syncthreads();
#pragma unroll
    for (int kk = 0; kk < 2; ++kk) {
      const u16x8 u = *(const u16x8*)&sP[(wave * 16 + l16) * RS + (kk * 4 + quad) * 8];
      u16x8 w;
#pragma unroll
      for (int e = 0; e < 8; ++e)
        w[e] = f2bf(__bfloat162float(__builtin_bit_cast(bf16, (ushort_t)u[e])) * 0.125f);
      const bf16x8 f = __builtin_bit_cast(bf16x8, w);
      if (tile) qfB[kk] = f; else qfA[kk] = f;
    }
    __syncthreads();
  }

  float mA = -1e30f, lA = 0.f, mB = -1e30f, lB = 0.f;
  f32x4 oA[4], oB[4];
#pragma unroll
  for (int dt = 0; dt < 4; ++dt) {
    oA[dt] = ZERO4;
    oB[dt] = ZERO4;
  }
  const int qgA = qtA * 64 + wave * 16 + l16;
  const int qgB = qtB * 64 + wave * 16 + l16;
  const int qmA = qtA * 64 + wave * 16;  // wave-min q row (mask hoist)
  const int qmB = qtB * 64 + wave * 16;

  // T14 async-stage: K/V tile kv+1 prefetched into regs during tile kv compute.
  u16x8 kr[2], vr[2];
#pragma unroll
  for (int t2 = 0; t2 < 2; ++t2) {
    const int idx = t2 * 256 + tid;
    const int r = idx >> 3, c = idx & 7;
    kr[t2] = *(const u16x8*)(Kg + base + (size_t)r * 64 + c * 8);
    vr[t2] = *(const u16x8*)(Vt + base + (size_t)r * 2048 + c * 8);
  }

  for (int kv = 0; kv <= qtB; ++kv) {
    __syncthreads();  // all waves done reading sK/sV of previous tile (drains lgkm)
#pragma unroll
    for (int t2 = 0; t2 < 2; ++t2) {
      const int idx = t2 * 256 + tid;
      const int r = idx >> 3, c = idx & 7;
      *(u16x8*)&sK[r * RS + c * 8] = kr[t2];
      *(u16x8*)&sV[r * RS + c * 8] = vr[t2];
    }
    __syncthreads();  // LDS visible (drains lgkm -> prior P reads complete too)
    if (kv < qtB) {   // issue next-tile loads AFTER the barrier (barrier drains
      const int kn = kv + 1;  // vmcnt; issuing here keeps them in flight under compute)
#pragma unroll
      for (int t2 = 0; t2 < 2; ++t2) {
        const int idx = t2 * 256 + tid;
        const int r = idx >> 3, c = idx & 7;
        kr[t2] = *(const u16x8*)(Kg + base + (size_t)(kn * 64 + r) * 64 + c * 8);
        vr[t2] = *(const u16x8*)(Vt + base + (size_t)r * 2048 + kn * 64 + c * 8);
      }
    }

    const bool doA = (kv <= qtA);  // block-uniform
    // ---- fused QK phase: kf read once, feeds both q-tiles ----
    f32x4 sSB[4], sSA[4];
#pragma unroll
    for (int nt = 0; nt < 4; ++nt) {
      const ushort_t* krow = &sK[(nt * 16 + l16) * RS + quad * 8];
      const bf16x8 kf0 = ld_frag(krow);
      const bf16x8 kf1 = ld_frag(krow + 32);  // (kk=1): (4+quad)*8 = quad*8+32
      sSB[nt] = MFMA16(kf0, qfB[0], ZERO4);
      sSB[nt] = MFMA16(kf1, qfB[1], sSB[nt]);
      if (doA) {
        sSA[nt] = MFMA16(kf0, qfA[0], ZERO4);
        sSA[nt] = MFMA16(kf1, qfA[1], sSA[nt]);
      }
    }
    const int kb = kv * 64 + quad * 4;
    softmax_tile(sSB, kb, qgB, kv * 64 + 63 > qmB, mB, lB, oB);
    if (doA) softmax_tile(sSA, kb, qgA, kv * 64 + 63 > qmA, mA, lA, oA);

    // ---- P writes to private regions (WAR-safe via staging barriers) ----
#pragma unroll
    for (int nt = 0; nt < 4; ++nt) {
      u16x4 pk;
#pragma unroll
      for (int reg = 0; reg < 4; ++reg) pk[reg] = f2bf(sSB[nt][reg]);
      *(u16x4*)&sPwB[l16 * RS + nt * 16 + quad * 4] = pk;
    }
    if (doA) {
#pragma unroll
      for (int nt = 0; nt < 4; ++nt) {
        u16x4 pk;
#pragma unroll
        for (int reg = 0; reg < 4; ++reg) pk[reg] = f2bf(sSA[nt][reg]);
        *(u16x4*)&sPwA[l16 * RS + nt * 16 + quad * 4] = pk;
      }
    }
    asm volatile("s_waitcnt lgkmcnt(0)" ::: "memory");  // single RAW drain
    bf16x8 pfB[2], pfA[2];
#pragma unroll
    for (int kk = 0; kk < 2; ++kk)
      pfB[kk] = ld_frag(&sPwB[l16 * RS + kk * 32 + quad * 8]);
    if (doA) {
#pragma unroll
      for (int kk = 0; kk < 2; ++kk)
        pfA[kk] = ld_frag(&sPwA[l16 * RS + kk * 32 + quad * 8]);
    }

    // ---- fused PV phase: vf read once, feeds both q-tiles ----
#pragma unroll
    for (int dt = 0; dt < 4; ++dt) {
      const ushort_t* vrow = &sV[(dt * 16 + l16) * RS + quad * 8];
      const bf16x8 vf0 = ld_frag(vrow);
      const bf16x8 vf1 = ld_frag(vrow + 32);
      oB[dt] = MFMA16(vf0, pfB[0], oB[dt]);
      oB[dt] = MFMA16(vf1, pfB[1], oB[dt]);
      if (doA) {
        oA[dt] = MFMA16(vf0, pfA[0], oA[dt]);
        oA[dt] = MFMA16(vf1, pfA[1], oA[dt]);
      }
    }
  }

  const int b = bh >> 4, h = bh & 15;
#pragma unroll
  for (int tile = 0; tile < 2; ++tile) {
    const int qt = tile ? qtB : qtA;
    const float linv = 1.f / (tile ? lB : lA);
    const f32x4* o = tile ? oB : oA;
    const int t = qt * 64 + wave * 16 + l16;
#pragma unroll
    for (int dt = 0; dt < 4; ++dt) {
      u16x4 pk;
#pragma unroll
      for (int reg = 0; reg < 4; ++reg) pk[reg] = f2bf(o[dt][reg] * linv);
      *(u16x4*)&Yg[(((size_t)b * 2048 + t) * 16 + h) * 64 + dt * 16 + quad * 4] = pk;
    }
  }
}

extern "C" void kernel_launch(void* const* d_in, const int* in_sizes, int n_in,
                              void* d_out, int out_size, void* d_ws, size_t ws_size,
                              hipStream_t stream) {
  const void* x = d_in[0];      // [4,2048,1024] fp32
  const void* w_qkv = d_in[1];  // [3072,1024] fp32
  const void* w_out = d_in[2];  // [1024,1024] fp32
  float* out = (float*)d_out;   // [4,2048,1024] fp32

  const size_t per = (size_t)4 * 16 * 2048 * 64;  // 8.39M elems
  const size_t nwqkv = (size_t)3072 * 1024;       // 3.15M
  const size_t nwout = (size_t)1024 * 1024;       // 1.05M
  ushort_t* qws = (ushort_t*)d_ws;   // [B,H,T,D]
  ushort_t* kws = qws + per;         // [B,H,T,D]
  ushort_t* vTws = kws + per;        // [B,H,D,T]
  ushort_t* xyws = vTws + per;       // xbf for gemm1, then y [B,T,H,D]
  ushort_t* wqkvb = xyws + per;      // bf16 w_qkv
  ushort_t* woutb = wqkvb + nwqkv;   // bf16 w_out
  int* flag = (int*)(woutb + nwout);
  const size_t need = (size_t)(4 * per + nwqkv + nwout) * 2 + 16;
  const bool pre = ws_size >= need;  // stable across calls (graph-safe)
  (void)in_sizes; (void)n_in; (void)out_size;

  dim3 blk(256);
  if (!pre) flag = (int*)(xyws + per);
  detect_dtype<<<1, 256, 0, stream>>>((const ushort_t*)x, flag);
  cvt_to_bf16<<<4096, 256, 0, stream>>>(x, xyws, (int)per, flag);
  if (pre) {
    cvt_to_bf16<<<1536, 256, 0, stream>>>(w_qkv, wqkvb, (int)nwqkv, flag);
    cvt_to_bf16<<<512, 256, 0, stream>>>(w_out, woutb, (int)nwout, flag);
    gemm_nt<1><<<dim3(24, 64), blk, 0, stream>>>(xyws, wqkvb, flag, 0, nullptr,
                                                 qws, kws, vTws, 8192, 3072, 1024);
    attn_causal<<<dim3(16, 64), blk, 0, stream>>>(qws, kws, vTws, xyws);
    gemm_nt<0><<<dim3(8, 64), blk, 0, stream>>>(xyws, woutb, flag, 0, out,
                                                nullptr, nullptr, nullptr,
                                                8192, 1024, 1024);
  } else {
    gemm_nt<1><<<dim3(24, 64), blk, 0, stream>>>(xyws, w_qkv, flag, 1, nullptr,
                                                 qws, kws, vTws, 8192, 3072, 1024);
    attn_causal<<<dim3(16, 64), blk, 0, stream>>>(qws, kws, vTws, xyws);
    gemm_nt<0><<<dim3(8, 64), blk, 0, stream>>>(xyws, w_out, flag, 1, out,
                                                nullptr, nullptr, nullptr,
                                                8192, 1024, 1024);
  }
}

// Round 5
// 264.837 us; speedup vs baseline: 1.1210x; 1.1210x over previous
//
#include <hip/hip_runtime.h>
#include <hip/hip_bf16.h>
#include <stdint.h>

// TemporalAttention: x[B,T,C] -> qkv proj -> causal MHA -> out proj.
// B=4 T=2048 C=1024 H=16 D=64. Inputs fp32, output fp32; internal bf16 MFMA.
//
// R10 post-mortem: fused variants serialized the chain and spilled
// (WRITE_SIZE 16->100MB). R8 (84us) is ~on its LDS-pipe roofline
// (~590 cyc/wave-iter x 400 wave-iters/CU ~= wall). R11: keep R8's
// unfused structure; cut LDS work mechanically:
//  - gl2lds double-buffered K/V staging (no ds_writes, no kr/vr regs,
//    ONE barrier/iter; loads span the full compute phase)
//  - linear [64][64] LDS + 16B XOR swizzle (rule 21: linear dest +
//    inverse-swizzled global SOURCE + swizzled reads) -> reads at
//    structural-minimum bank occupancy
//  - P roundtrip in an 8KB swizzled region; Q direct from global.
//  LDS = 16K(sK) + 16K(sV) + 8K(sP) = 40960B = exactly 4 blocks/CU.

using bf16 = __hip_bfloat16;
typedef __attribute__((ext_vector_type(8))) __bf16 bf16x8;
typedef __attribute__((ext_vector_type(8))) unsigned short u16x8;
typedef __attribute__((ext_vector_type(4))) unsigned short u16x4;
typedef __attribute__((ext_vector_type(4))) float f32x4;
typedef unsigned short ushort_t;

#define MFMA16(a, b, c) __builtin_amdgcn_mfma_f32_16x16x32_bf16((a), (b), (c), 0, 0, 0)

__device__ __forceinline__ bf16x8 ld_frag(const ushort_t* p) {
  const u16x8 u = *(const u16x8*)p;
  return __builtin_bit_cast(bf16x8, u);
}

__device__ __forceinline__ ushort_t f2bf(float f) {
  return __builtin_bit_cast(ushort_t, __float2bfloat16(f));
}

// async global->LDS, 16B/lane; lds base wave-uniform, lane l -> base+l*16.
__device__ __forceinline__ void gl2lds16(const void* g, void* lds) {
  __builtin_amdgcn_global_load_lds((const __attribute__((address_space(1))) void*)g,
                                   (__attribute__((address_space(3))) void*)lds,
                                   16, 0, 0);
}

// ---------------------------------------------------------------------------
// Dtype detector (hedge; fp32 established). flag=1 -> fp32.
// ---------------------------------------------------------------------------
__global__ void detect_dtype(const ushort_t* __restrict__ x, int* __restrict__ flag) {
  __shared__ int red[256];
  const int tid = threadIdx.x;
  int cnt = 0;
  for (int i = tid; i < 4096; i += 256) {
    const int e = (x[i] & 0x7FFF) >> 7;
    cnt += (e >= 117 && e <= 133) ? 1 : 0;
  }
  red[tid] = cnt;
  __syncthreads();
  for (int s = 128; s > 0; s >>= 1) {
    if (tid < s) red[tid] += red[tid + s];
    __syncthreads();
  }
  if (tid == 0) *flag = (red[0] < 3072) ? 1 : 0;
}

// ---------------------------------------------------------------------------
// fp32 -> bf16 (or copy if flag==0). n multiple of 2048.
// ---------------------------------------------------------------------------
__global__ void cvt_to_bf16(const void* __restrict__ in, ushort_t* __restrict__ out,
                            int n, const int* __restrict__ flag) {
  const int i = (blockIdx.x * 256 + threadIdx.x) * 8;
  if (i >= n) return;
  if (*flag) {
    const float* p = (const float*)in + i;
    const float4 f0 = *(const float4*)p;
    const float4 f1 = *(const float4*)(p + 4);
    u16x8 u;
    u[0] = f2bf(f0.x); u[1] = f2bf(f0.y); u[2] = f2bf(f0.z); u[3] = f2bf(f0.w);
    u[4] = f2bf(f1.x); u[5] = f2bf(f1.y); u[6] = f2bf(f1.z); u[7] = f2bf(f1.w);
    *(u16x8*)(out + i) = u;
  } else {
    *(u16x8*)(out + i) = *(const u16x8*)((const ushort_t*)in + i);
  }
}

// ---------------------------------------------------------------------------
// NT GEMM: C[M,N] = A[M,K]*B[N,K]^T. 128x128 tile, 4 waves 2x2, BK=32,
// 16x16x32 bf16 MFMA. A: bf16, gl2lds staging (m97-verbatim, plain layout).
// B: bf16 via gl2lds when bF==0; fp32 register-staged+cvt when bF==1
// (ws-starved fallback). EPI==0: fp32 store. EPI==1: scatter q/k [B,H,T,D],
// V transposed [B,H,D,T].
// ---------------------------------------------------------------------------
template <int EPI>
__global__ __launch_bounds__(256, 2)
void gemm_nt(const ushort_t* __restrict__ A, const void* __restrict__ Bw,
             const int* __restrict__ flag, int bExt,
             float* __restrict__ C0, ushort_t* __restrict__ Qo,
             ushort_t* __restrict__ Ko, ushort_t* __restrict__ Vt,
             int M, int N, int Kd) {
  __shared__ ushort_t sA[128 * 32];
  __shared__ ushort_t sB[128 * 32];
  const int tid = threadIdx.x;
  const int wave = tid >> 6, lane = tid & 63;
  const int quad = lane >> 4, l16 = lane & 15;
  const int wm = wave >> 1, wn = wave & 1;
  const long m0 = (long)blockIdx.y * 128;
  const long n0 = (long)blockIdx.x * 128;
  const int bF = bExt ? *flag : 0;

  f32x4 acc[4][4];
#pragma unroll
  for (int i = 0; i < 4; ++i)
#pragma unroll
    for (int j = 0; j < 4; ++j) acc[i][j] = (f32x4){0.f, 0.f, 0.f, 0.f};

  for (int k0 = 0; k0 < Kd; k0 += 32) {
#pragma unroll
    for (int j = 0; j < 2; ++j) {
      const int chunk = wave * 2 + j;     // wave-uniform LDS base
      const int idx = chunk * 64 + lane;  // 0..511: 16B chunk per lane
      const int r = idx >> 2, c = idx & 3;
      gl2lds16(A + (m0 + r) * (long)Kd + k0 + c * 8, (char*)sA + chunk * 1024);
    }
    if (!bF) {
#pragma unroll
      for (int j = 0; j < 2; ++j) {
        const int chunk = wave * 2 + j;
        const int idx = chunk * 64 + lane;
        const int r = idx >> 2, c = idx & 3;
        gl2lds16((const ushort_t*)Bw + (n0 + r) * (long)Kd + k0 + c * 8,
                 (char*)sB + chunk * 1024);
      }
    } else {
#pragma unroll
      for (int t2 = 0; t2 < 2; ++t2) {
        const int idx = t2 * 256 + tid;
        const int r = idx >> 2, c = idx & 3;
        const float* p = (const float*)Bw + (n0 + r) * (long)Kd + k0 + c * 8;
        const float4 f0 = *(const float4*)p;
        const float4 f1 = *(const float4*)(p + 4);
        u16x8 u;
        u[0] = f2bf(f0.x); u[1] = f2bf(f0.y); u[2] = f2bf(f0.z); u[3] = f2bf(f0.w);
        u[4] = f2bf(f1.x); u[5] = f2bf(f1.y); u[6] = f2bf(f1.z); u[7] = f2bf(f1.w);
        *(u16x8*)&sB[r * 32 + c * 8] = u;
      }
    }
    __syncthreads();
    bf16x8 af[4], bfr[4];
#pragma unroll
    for (int i = 0; i < 4; ++i) {
      const int r = wm * 64 + i * 16 + l16;
      af[i] = ld_frag(&sA[r * 32 + quad * 8]);
    }
#pragma unroll
    for (int i = 0; i < 4; ++i) {
      const int r = wn * 64 + i * 16 + l16;
      bfr[i] = ld_frag(&sB[r * 32 + quad * 8]);
    }
#pragma unroll
    for (int i = 0; i < 4; ++i)
#pragma unroll
      for (int j = 0; j < 4; ++j) acc[i][j] = MFMA16(af[i], bfr[j], acc[i][j]);
    __syncthreads();
  }

  // epilogue: C/D layout col=lane&15, row=quad*4+reg (m89-verified)
#pragma unroll
  for (int i = 0; i < 4; ++i) {
#pragma unroll
    for (int j = 0; j < 4; ++j) {
      if (EPI == 0) {
#pragma unroll
        for (int reg = 0; reg < 4; ++reg) {
          const long m = m0 + wm * 64 + i * 16 + quad * 4 + reg;
          const long n = n0 + wn * 64 + j * 16 + l16;
          C0[m * N + n] = acc[i][j][reg];
        }
      } else {
        const long n = n0 + wn * 64 + j * 16 + l16;
        const int which = (int)(n >> 10);  // block-uniform
        const int h = (int)((n >> 6) & 15);
        const int d = (int)(n & 63);
        const long mbase = m0 + wm * 64 + i * 16 + quad * 4;
        const long b = mbase >> 11;
        const long tb = mbase & 2047;
        if (which == 2) {
          u16x4 pk;
#pragma unroll
          for (int reg = 0; reg < 4; ++reg) pk[reg] = f2bf(acc[i][j][reg]);
          *(u16x4*)&Vt[((b * 16 + h) * 64 + d) * 2048 + tb] = pk;
        } else {
          ushort_t* dst = (which == 0) ? Qo : Ko;
#pragma unroll
          for (int reg = 0; reg < 4; ++reg)
            dst[((b * 16 + h) * 2048 + tb + reg) * 64 + d] = f2bf(acc[i][j][reg]);
        }
      }
    }
  }
}

// ---------------------------------------------------------------------------
// Flash attention (causal), S^T/O^T formulation. R11 structure:
// unfused A/B jobs (R8-proven), gl2lds double-buffered K/V in swizzled-
// linear [64][64] LDS tiles, one barrier/iter, P in swizzled 8KB region,
// Q direct from global. Swizzle: within-row byte ^= ((row&7)<<4); gl2lds
// writes linear so the global SOURCE is pre-swizzled (rule 21).
// ---------------------------------------------------------------------------

// softmax over S^T tile held in s[4] (keys = kb+nt*16+reg, q col = l16).
// Mutates s to P values; updates m_i, l_i; rescales oacc on max growth.
__device__ __forceinline__ void softmax_tile(f32x4* s, int kb, int qg, bool need_mask,
                                             float& m_i, float& l_i, f32x4* oacc) {
  float rmax = -1e30f;
  if (need_mask) {  // diagonal tiles only (wave-uniform)
#pragma unroll
    for (int nt = 0; nt < 4; ++nt) {
#pragma unroll
      for (int reg = 0; reg < 4; ++reg) {
        float v = s[nt][reg];
        if (kb + nt * 16 + reg > qg) v = -1e30f;
        s[nt][reg] = v;
        rmax = fmaxf(rmax, v);
      }
    }
  } else {
#pragma unroll
    for (int nt = 0; nt < 4; ++nt) {
#pragma unroll
      for (int reg = 0; reg < 4; ++reg) rmax = fmaxf(rmax, s[nt][reg]);
    }
  }
  rmax = fmaxf(rmax, __shfl_xor(rmax, 16, 64));
  rmax = fmaxf(rmax, __shfl_xor(rmax, 32, 64));
  float mnew = fmaxf(m_i, rmax);
  if (__all(rmax - m_i <= 5.5f)) {
    mnew = m_i;  // defer-max: P bounded by e^5.5 ~ 245, f32 accum tolerates
  } else {
    const float alpha = __expf(m_i - mnew);
    l_i *= alpha;
#pragma unroll
    for (int dt = 0; dt < 4; ++dt) oacc[dt] *= alpha;
    m_i = mnew;
  }
  float rs = 0.f;
#pragma unroll
  for (int nt = 0; nt < 4; ++nt) {
#pragma unroll
    for (int reg = 0; reg < 4; ++reg) {
      const float p = __expf(s[nt][reg] - mnew);
      s[nt][reg] = p;
      rs += p;
    }
  }
  rs += __shfl_xor(rs, 16, 64);
  rs += __shfl_xor(rs, 32, 64);
  l_i += rs;
}

// one q-tile job: QK^T -> softmax -> P roundtrip -> PV. sKc/sVc are the
// current swizzled [64][64] tiles; sPw is this wave's private P region.
__device__ __forceinline__ void attn_job(const bf16x8 qf[2], const ushort_t* sKc,
                                         const ushort_t* sVc, ushort_t* sPw,
                                         int kv, int qg, bool need_mask,
                                         int quad, int l8, int l16,
                                         float& m_i, float& l_i, f32x4* oacc) {
  const f32x4 ZERO4 = {0.f, 0.f, 0.f, 0.f};
  const int off0 = ((quad ^ l8) << 3);        // col16=quad   (kk=0), swizzled
  const int off1 = (((quad + 4) ^ l8) << 3);  // col16=quad+4 (kk=1), swizzled
  f32x4 s[4];
#pragma unroll
  for (int nt = 0; nt < 4; ++nt) {
    const ushort_t* krow = sKc + (nt * 16 + l16) * 64;
    s[nt] = MFMA16(ld_frag(krow + off0), qf[0], ZERO4);
    s[nt] = MFMA16(ld_frag(krow + off1), qf[1], s[nt]);
  }
  softmax_tile(s, kv * 64 + quad * 4, qg, need_mask, m_i, l_i, oacc);

  asm volatile("s_waitcnt lgkmcnt(0)" ::: "memory");  // WAR: prior sPw reads done
#pragma unroll
  for (int nt = 0; nt < 4; ++nt) {
    u16x4 pk;
#pragma unroll
    for (int reg = 0; reg < 4; ++reg) pk[reg] = f2bf(s[nt][reg]);
    // write elem (4*(4nt+quad)) ^ (l8<<3) of row l16 (swizzled, 8B-aligned)
    *(u16x4*)&sPw[l16 * 64 + (((4 * nt + quad) << 2) ^ (l8 << 3))] = pk;
  }
  asm volatile("s_waitcnt lgkmcnt(0)" ::: "memory");  // RAW: writes visible
  bf16x8 pf0 = ld_frag(&sPw[l16 * 64 + off0]);
  bf16x8 pf1 = ld_frag(&sPw[l16 * 64 + off1]);
#pragma unroll
  for (int dt = 0; dt < 4; ++dt) {
    const ushort_t* vrow = sVc + (dt * 16 + l16) * 64;
    oacc[dt] = MFMA16(ld_frag(vrow + off0), pf0, oacc[dt]);
    oacc[dt] = MFMA16(ld_frag(vrow + off1), pf1, oacc[dt]);
  }
}

__global__ __launch_bounds__(256, 4)
void attn_causal(const ushort_t* __restrict__ Qg, const ushort_t* __restrict__ Kg,
                 const ushort_t* __restrict__ Vt, ushort_t* __restrict__ Yg) {
  __shared__ ushort_t sK[2][64 * 64];  // swizzled-linear tiles, dbuf
  __shared__ ushort_t sV[2][64 * 64];
  __shared__ ushort_t sP[64 * 64];     // per-wave 16-row P regions
  const int tid = threadIdx.x;
  const int wave = tid >> 6, lane = tid & 63;
  const int quad = lane >> 4, l16 = lane & 15, l8 = lane & 7;
  const f32x4 ZERO4 = {0.f, 0.f, 0.f, 0.f};
  // XCD-aware bijective remap: XCD k owns bh in [8k,8k+8) -> 4MB KV = L2.
  const int lin = blockIdx.y * 16 + blockIdx.x;
  const int logical = (lin & 7) * 128 + (lin >> 3);
  const int qx = logical & 15, bh = logical >> 4;
  const int qtA = qx, qtB = 31 - qx;
  const size_t base = (size_t)bh * 2048 * 64;
  ushort_t* sPw = sP + wave * 16 * 64;

  // staging geometry: chunk = 8 rows x 128B; lane l -> row chunk*8+(l>>3),
  // LDS bytes (l&7)*16. Pre-swizzled SOURCE col so swizzled reads match:
  // src col8 = (l&7) ^ ((l>>3)&7).
  const int srow = lane >> 3;                    // row within chunk
  const int scol = ((lane & 7) ^ srow) << 3;     // src col in elems (x8)

  // Q fragments direct from global, pre-scaled by 1/sqrt(64)=0.125 (exact)
  bf16x8 qfA[2], qfB[2];
#pragma unroll
  for (int tile = 0; tile < 2; ++tile) {
    const int qt = tile ? qtB : qtA;
    const size_t qrow = base + (size_t)(qt * 64 + wave * 16 + l16) * 64;
#pragma unroll
    for (int kk = 0; kk < 2; ++kk) {
      const u16x8 u = *(const u16x8*)(Qg + qrow + (kk * 4 + quad) * 8);
      u16x8 w;
#pragma unroll
      for (int e = 0; e < 8; ++e)
        w[e] = f2bf(__bfloat162float(__builtin_bit_cast(bf16, (ushort_t)u[e])) * 0.125f);
      const bf16x8 f = __builtin_bit_cast(bf16x8, w);
      if (tile) qfB[kk] = f; else qfA[kk] = f;
    }
  }

  float mA = -1e30f, lA = 0.f, mB = -1e30f, lB = 0.f;
  f32x4 oA[4], oB[4];
#pragma unroll
  for (int dt = 0; dt < 4; ++dt) {
    oA[dt] = ZERO4;
    oB[dt] = ZERO4;
  }
  const int qgA = qtA * 64 + wave * 16 + l16;
  const int qgB = qtB * 64 + wave * 16 + l16;
  const int qmA = qtA * 64 + wave * 16;  // wave-min q row (mask hoist)
  const int qmB = qtB * 64 + wave * 16;

  // prologue: stage tile 0 into buf 0 (async; drained by first barrier)
#pragma unroll
  for (int j = 0; j < 2; ++j) {
    const int chunk = wave * 2 + j;  // wave-uniform
    gl2lds16(Kg + base + (size_t)(chunk * 8 + srow) * 64 + scol,
             (char*)&sK[0][0] + chunk * 1024);
    gl2lds16(Vt + base + (size_t)(chunk * 8 + srow) * 2048 + scol,
             (char*)&sV[0][0] + chunk * 1024);
  }

  for (int kv = 0; kv <= qtB; ++kv) {
    const int cur = kv & 1;
    __syncthreads();  // drains vmcnt: buf[cur] filled; all waves past reads of buf[cur^1]
    if (kv < qtB) {   // async-stage tile kv+1 into the other buffer
      const int kn = kv + 1;
#pragma unroll
      for (int j = 0; j < 2; ++j) {
        const int chunk = wave * 2 + j;
        gl2lds16(Kg + base + (size_t)(kn * 64 + chunk * 8 + srow) * 64 + scol,
                 (char*)&sK[cur ^ 1][0] + chunk * 1024);
        gl2lds16(Vt + base + (size_t)(chunk * 8 + srow) * 2048 + kn * 64 + scol,
                 (char*)&sV[cur ^ 1][0] + chunk * 1024);
      }
    }
    const ushort_t* sKc = &sK[cur][0];
    const ushort_t* sVc = &sV[cur][0];
    attn_job(qfB, sKc, sVc, sPw, kv, qgB, kv * 64 + 63 > qmB, quad, l8, l16, mB, lB, oB);
    if (kv <= qtA)
      attn_job(qfA, sKc, sVc, sPw, kv, qgA, kv * 64 + 63 > qmA, quad, l8, l16, mA, lA, oA);
  }

  const int b = bh >> 4, h = bh & 15;
#pragma unroll
  for (int tile = 0; tile < 2; ++tile) {
    const int qt = tile ? qtB : qtA;
    const float linv = 1.f / (tile ? lB : lA);
    const f32x4* o = tile ? oB : oA;
    const int t = qt * 64 + wave * 16 + l16;
#pragma unroll
    for (int dt = 0; dt < 4; ++dt) {
      u16x4 pk;
#pragma unroll
      for (int reg = 0; reg < 4; ++reg) pk[reg] = f2bf(o[dt][reg] * linv);
      *(u16x4*)&Yg[(((size_t)b * 2048 + t) * 16 + h) * 64 + dt * 16 + quad * 4] = pk;
    }
  }
}

extern "C" void kernel_launch(void* const* d_in, const int* in_sizes, int n_in,
                              void* d_out, int out_size, void* d_ws, size_t ws_size,
                              hipStream_t stream) {
  const void* x = d_in[0];      // [4,2048,1024] fp32
  const void* w_qkv = d_in[1];  // [3072,1024] fp32
  const void* w_out = d_in[2];  // [1024,1024] fp32
  float* out = (float*)d_out;   // [4,2048,1024] fp32

  const size_t per = (size_t)4 * 16 * 2048 * 64;  // 8.39M elems
  const size_t nwqkv = (size_t)3072 * 1024;       // 3.15M
  const size_t nwout = (size_t)1024 * 1024;       // 1.05M
  ushort_t* qws = (ushort_t*)d_ws;   // [B,H,T,D]
  ushort_t* kws = qws + per;         // [B,H,T,D]
  ushort_t* vTws = kws + per;        // [B,H,D,T]
  ushort_t* xyws = vTws + per;       // xbf for gemm1, then y [B,T,H,D]
  ushort_t* wqkvb = xyws + per;      // bf16 w_qkv
  ushort_t* woutb = wqkvb + nwqkv;   // bf16 w_out
  int* flag = (int*)(woutb + nwout);
  const size_t need = (size_t)(4 * per + nwqkv + nwout) * 2 + 16;
  const bool pre = ws_size >= need;  // stable across calls (graph-safe)
  (void)in_sizes; (void)n_in; (void)out_size;

  dim3 blk(256);
  if (!pre) flag = (int*)(xyws + per);
  detect_dtype<<<1, 256, 0, stream>>>((const ushort_t*)x, flag);
  cvt_to_bf16<<<4096, 256, 0, stream>>>(x, xyws, (int)per, flag);
  if (pre) {
    cvt_to_bf16<<<1536, 256, 0, stream>>>(w_qkv, wqkvb, (int)nwqkv, flag);
    cvt_to_bf16<<<512, 256, 0, stream>>>(w_out, woutb, (int)nwout, flag);
    gemm_nt<1><<<dim3(24, 64), blk, 0, stream>>>(xyws, wqkvb, flag, 0, nullptr,
                                                 qws, kws, vTws, 8192, 3072, 1024);
    attn_causal<<<dim3(16, 64), blk, 0, stream>>>(qws, kws, vTws, xyws);
    gemm_nt<0><<<dim3(8, 64), blk, 0, stream>>>(xyws, woutb, flag, 0, out,
                                                nullptr, nullptr, nullptr,
                                                8192, 1024, 1024);
  } else {
    gemm_nt<1><<<dim3(24, 64), blk, 0, stream>>>(xyws, w_qkv, flag, 1, nullptr,
                                                 qws, kws, vTws, 8192, 3072, 1024);
    attn_causal<<<dim3(16, 64), blk, 0, stream>>>(qws, kws, vTws, xyws);
    gemm_nt<0><<<dim3(8, 64), blk, 0, stream>>>(xyws, w_out, flag, 1, out,
                                                nullptr, nullptr, nullptr,
                                                8192, 1024, 1024);
  }
}